// Round 9
// baseline (1754.918 us; speedup 1.0000x reference)
//
#include <hip/hip_runtime.h>
#include <hip/hip_bf16.h>

#define NLAYER 12
#define DMODEL 768
#define NHEAD  12
#define HDIM   64
#define FDIM   3072
#define VOCAB  30522
#define SLEN   512
#define NBATCH 4
#define NTOK   (NBATCH*SLEN)
#define EPSLN  1e-5f

typedef unsigned short u16;
using bf16 = __hip_bfloat16;
typedef __bf16 bf16x8 __attribute__((ext_vector_type(8)));
typedef float  f32x4  __attribute__((ext_vector_type(4)));
typedef u16    u16x4  __attribute__((ext_vector_type(4)));

__device__ __forceinline__ u16 f2bs(float f) {
    bf16 h = __float2bfloat16(f);
    return *reinterpret_cast<u16*>(&h);
}

// async global->LDS, 16B per lane. LDS dest = wave-uniform base + lane*16.
__device__ __forceinline__ void gload_lds16(const void* g, void* l) {
    auto gp = (const __attribute__((address_space(1))) unsigned int*)g;
    auto lp = (__attribute__((address_space(3))) unsigned int*)(unsigned long long)l;
    __builtin_amdgcn_global_load_lds(gp, lp, 16, 0, 0);
}

template<int N> __device__ __forceinline__ void waitv() {
    if constexpr (N == 0)      asm volatile("s_waitcnt vmcnt(0)" ::: "memory");
    else if constexpr (N == 3) asm volatile("s_waitcnt vmcnt(3)" ::: "memory");
    else if constexpr (N == 4) asm volatile("s_waitcnt vmcnt(4)" ::: "memory");
    else if constexpr (N == 6) asm volatile("s_waitcnt vmcnt(6)" ::: "memory");
    else if constexpr (N == 8) asm volatile("s_waitcnt vmcnt(8)" ::: "memory");
}

// ---------------- reductions ----------------
__device__ __forceinline__ float wave_sum64(float v) {
#pragma unroll
    for (int off = 32; off > 0; off >>= 1) v += __shfl_down(v, off, 64);
    return v;
}
__device__ __forceinline__ float block_sum256(float v, float* red) {
    v = wave_sum64(v);
    __syncthreads();
    if ((threadIdx.x & 63) == 0) red[threadIdx.x >> 6] = v;
    __syncthreads();
    return red[0] + red[1] + red[2] + red[3];
}

// ---------------- embedding + LN (writes f32 + bf16) ----------------
__global__ __launch_bounds__(256) void embed_ln_kernel(
    const int* __restrict__ ids, const float* __restrict__ word,
    const float* __restrict__ pos, const float* __restrict__ seg,
    const float* __restrict__ g, const float* __restrict__ b,
    float* __restrict__ out, u16* __restrict__ outb)
{
    __shared__ float red[4];
    int t = blockIdx.x;
    int s = t & (SLEN - 1);
    long woff = (long)ids[t] * DMODEL;
    float vals[3];
#pragma unroll
    for (int i = 0; i < 3; i++) {
        int d = threadIdx.x + i * 256;
        vals[i] = word[woff + d] + pos[(long)s * DMODEL + d] + seg[d];
    }
    float mu = block_sum256(vals[0] + vals[1] + vals[2], red) * (1.0f / DMODEL);
    float vv = 0.f;
#pragma unroll
    for (int i = 0; i < 3; i++) { float d0 = vals[i] - mu; vv += d0 * d0; }
    float rstd = rsqrtf(block_sum256(vv, red) * (1.0f / DMODEL) + EPSLN);
#pragma unroll
    for (int i = 0; i < 3; i++) {
        int d = threadIdx.x + i * 256;
        float r = (vals[i] - mu) * rstd * g[d] + b[d];
        out[(long)t * DMODEL + d] = r;
        outb[(long)t * DMODEL + d] = f2bs(r);
    }
}

// ------------- residual + 2 partials (+opt bias) + LN ----------------------
__global__ __launch_bounds__(256) void ln_res2_kernel(
    const float* __restrict__ a, const float* __restrict__ p0,
    const float* __restrict__ p1, const float* __restrict__ cbias,
    const float* __restrict__ g, const float* __restrict__ beta,
    float* __restrict__ out, u16* __restrict__ outb)
{
    __shared__ float red[4];
    long t = blockIdx.x;
    float vals[3];
#pragma unroll
    for (int i = 0; i < 3; i++) {
        int d = threadIdx.x + i * 256;
        float bb = cbias ? cbias[d] : 0.f;
        vals[i] = a[t * DMODEL + d] + p0[t * DMODEL + d] + p1[t * DMODEL + d] + bb;
    }
    float mu = block_sum256(vals[0] + vals[1] + vals[2], red) * (1.0f / DMODEL);
    float vv = 0.f;
#pragma unroll
    for (int i = 0; i < 3; i++) { float d0 = vals[i] - mu; vv += d0 * d0; }
    float rstd = rsqrtf(block_sum256(vv, red) * (1.0f / DMODEL) + EPSLN);
#pragma unroll
    for (int i = 0; i < 3; i++) {
        int d = threadIdx.x + i * 256;
        float r = (vals[i] - mu) * rstd * g[d] + beta[d];
        out[t * DMODEL + d] = r;
        outb[t * DMODEL + d] = f2bs(r);
    }
}

// ---------------- all-weights transpose-convert, ONE launch ----------------
#define DD (DMODEL*DMODEL)
#define DF (DMODEL*FDIM)
#define LAYER_W_ELEMS (4*DD + 2*DF)
#define TILES_DD 576
#define TILES_DF 2304
#define TILES_LAYER (4*TILES_DD + 2*TILES_DF)
#define TILES_ALL (NLAYER*TILES_LAYER)
#define NTX_OW ((VOCAB + 31) / 32)
#define TILES_OW (NTX_OW * (DMODEL/32))

__global__ __launch_bounds__(256) void conv_all_kernel(
    const float* __restrict__ Wq, const float* __restrict__ Wk,
    const float* __restrict__ Wv, const float* __restrict__ Wo,
    const float* __restrict__ F1w, const float* __restrict__ F2w,
    const float* __restrict__ OutW, u16* __restrict__ wT, u16* __restrict__ owT)
{
    __shared__ float t[32][33];
    int id = blockIdx.x;
    const float* src; u16* dst; int K, N, tt;
    if (id < TILES_ALL) {
        int l = id / TILES_LAYER, r = id - l * TILES_LAYER;
        u16* base = wT + (long)l * LAYER_W_ELEMS;
        if (r < TILES_DD)           { src = Wq  + (long)l * DD; dst = base;            K = DMODEL; N = DMODEL; tt = r; }
        else if (r < 2 * TILES_DD)  { src = Wk  + (long)l * DD; dst = base + DD;       K = DMODEL; N = DMODEL; tt = r - TILES_DD; }
        else if (r < 3 * TILES_DD)  { src = Wv  + (long)l * DD; dst = base + 2 * DD;   K = DMODEL; N = DMODEL; tt = r - 2 * TILES_DD; }
        else if (r < 4 * TILES_DD)  { src = Wo  + (long)l * DD; dst = base + 3 * DD;   K = DMODEL; N = DMODEL; tt = r - 3 * TILES_DD; }
        else if (r < 4 * TILES_DD + TILES_DF)
                                    { src = F1w + (long)l * DF; dst = base + 4 * DD;   K = DMODEL; N = FDIM;   tt = r - 4 * TILES_DD; }
        else                        { src = F2w + (long)l * DF; dst = base + 4 * DD + DF; K = FDIM; N = DMODEL; tt = r - 4 * TILES_DD - TILES_DF; }
    } else {
        src = OutW; dst = owT; K = DMODEL; N = VOCAB; tt = id - TILES_ALL;
    }
    int ntx = (N + 31) >> 5;
    int n0 = (tt % ntx) * 32, k0 = (tt / ntx) * 32;
    int tx = threadIdx.x & 31, ty = threadIdx.x >> 5;
#pragma unroll
    for (int i = 0; i < 32; i += 8) {
        int k = k0 + ty + i, n = n0 + tx;
        t[ty + i][tx] = (k < K && n < N) ? src[(long)k * N + n] : 0.f;
    }
    __syncthreads();
#pragma unroll
    for (int i = 0; i < 32; i += 8) {
        int n = n0 + ty + i, k = k0 + tx;
        if (n < N && k < K) dst[(long)n * K + k] = f2bs(t[tx][ty + i]);
    }
}

// -------- fused QK^T + mask + softmax + PV  (one kernel per 64 Q-rows) -----
// exp path: s2 = acc*(scale*log2e) + mask folded in-place; p = exp2(s2 - m2)
// via v_exp_f32 — mathematically identical to exp(s-m), ~1 ulp diffs.
__global__ __launch_bounds__(256, 2) void attn_kernel(
    const u16* __restrict__ qkvb, const u16* __restrict__ vtb,
    const int* __restrict__ amask,
    float* __restrict__ attn, u16* __restrict__ ob)
{
    __shared__ u16 Qs[64][64];
    __shared__ u16 Ks[SLEN][64];
    __shared__ float maskadd[SLEN];
    __shared__ __align__(16) float redA[64][4];
    __shared__ __align__(16) float redB[64][4];

    u16* Ph = &Ks[0][0];
    u16* Vh = &Ks[256][0];

    int z = blockIdx.y;
    int b = z / NHEAD, h = z - b * NHEAD;
    int m0 = blockIdx.x * 64;
    int tid = threadIdx.x;
    int wave = tid >> 6, lane = tid & 63;
    int quad = lane >> 4, l16 = lane & 15;
    const float scale2 = 0.036084391824351615f * 1.4426950408889634f; // (1/sqrt768)*log2e

    for (int i = tid; i < SLEN; i += 256)
        maskadd[i] = amask[b * SLEN + i] ? 0.f : -1e30f;

    const u16* Qbase = qkvb + (long)(b * SLEN) * (3 * DMODEL) + h * HDIM;
    const u16* Kbase = Qbase + DMODEL;
    const u16* Vtbase = vtb + (long)z * HDIM * SLEN;

#pragma unroll
    for (int i = 0; i < 2; i++) {
        int off = wave * 2048 + i * 1024 + lane * 16;
        int row = off >> 7, c = (off >> 4) & 7, g = c ^ (row & 7);
        gload_lds16(Qbase + (long)(m0 + row) * (3 * DMODEL) + g * 8,
                    (char*)&Qs[0][0] + wave * 2048 + i * 1024);
    }
#pragma unroll
    for (int i = 0; i < 16; i++) {
        int off = wave * 16384 + i * 1024 + lane * 16;
        int row = off >> 7, c = (off >> 4) & 7, g = c ^ (row & 7);
        gload_lds16(Kbase + (long)row * (3 * DMODEL) + g * 8,
                    (char*)&Ks[0][0] + wave * 16384 + i * 1024);
    }
    __syncthreads();

    f32x4 acc[4][8];
#pragma unroll
    for (int i = 0; i < 4; i++)
#pragma unroll
        for (int j = 0; j < 8; j++) acc[i][j] = (f32x4){0.f, 0.f, 0.f, 0.f};

#pragma unroll
    for (int ks = 0; ks < 2; ks++) {
        bf16x8 afr[4], bfr[8];
#pragma unroll
        for (int i = 0; i < 4; i++) {
            int row = i * 16 + l16;
            int slot = ((ks << 2) + quad) ^ (row & 7);
            afr[i] = *reinterpret_cast<const bf16x8*>((char*)&Qs[0][0] + row * 128 + slot * 16);
        }
#pragma unroll
        for (int j = 0; j < 8; j++) {
            int row = wave * 128 + j * 16 + l16;
            int slot = ((ks << 2) + quad) ^ (row & 7);
            bfr[j] = *reinterpret_cast<const bf16x8*>((char*)&Ks[0][0] + row * 128 + slot * 16);
        }
#pragma unroll
        for (int i = 0; i < 4; i++)
#pragma unroll
            for (int j = 0; j < 8; j++)
                acc[i][j] = __builtin_amdgcn_mfma_f32_16x16x32_bf16(afr[i], bfr[j], acc[i][j], 0, 0, 0);
    }

    // fold scale*log2e + mask into acc once (scaled-exp2 domain)
    {
        float ma[8];
#pragma unroll
        for (int j = 0; j < 8; j++) ma[j] = maskadd[wave * 128 + j * 16 + l16];
#pragma unroll
        for (int i = 0; i < 4; i++)
#pragma unroll
            for (int j = 0; j < 8; j++)
#pragma unroll
                for (int r = 0; r < 4; r++)
                    acc[i][j][r] = acc[i][j][r] * scale2 + ma[j];
    }

    float rmax[4][4];
#pragma unroll
    for (int i = 0; i < 4; i++)
#pragma unroll
        for (int r = 0; r < 4; r++) {
            float m = -3e38f;
#pragma unroll
            for (int j = 0; j < 8; j++) m = fmaxf(m, acc[i][j][r]);
            rmax[i][r] = m;
        }
#pragma unroll
    for (int off = 1; off < 16; off <<= 1)
#pragma unroll
        for (int i = 0; i < 4; i++)
#pragma unroll
            for (int r = 0; r < 4; r++)
                rmax[i][r] = fmaxf(rmax[i][r], __shfl_xor(rmax[i][r], off, 64));
    if (l16 == 0) {
#pragma unroll
        for (int i = 0; i < 4; i++)
#pragma unroll
            for (int r = 0; r < 4; r++) redA[i * 16 + quad * 4 + r][wave] = rmax[i][r];
    }
    __syncthreads();          // all waves done reading Ks; safe to restage V

    {
        const u16* Vb = Vtbase + 0;
#pragma unroll
        for (int i = 0; i < 8; i++) {
            int o = wave * 8192 + i * 1024 + lane * 16;
            int hd = o >> 9, c = (o >> 4) & 31, g = c ^ (hd & 7);
            gload_lds16(Vb + (long)hd * SLEN + g * 8, (char*)Vh + wave * 8192 + i * 1024);
        }
    }

#pragma unroll
    for (int i = 0; i < 4; i++)
#pragma unroll
        for (int r = 0; r < 4; r++) {
            f32x4 v = *reinterpret_cast<const f32x4*>(&redA[i * 16 + quad * 4 + r][0]);
            rmax[i][r] = fmaxf(fmaxf(v[0], v[1]), fmaxf(v[2], v[3]));
        }

    float rsum[4][4];
#pragma unroll
    for (int i = 0; i < 4; i++)
#pragma unroll
        for (int r = 0; r < 4; r++) {
            float s = 0.f;
#pragma unroll
            for (int j = 0; j < 8; j++) {
                float e = __builtin_amdgcn_exp2f(acc[i][j][r] - rmax[i][r]);
                acc[i][j][r] = e;
                s += e;
            }
            rsum[i][r] = s;
        }
#pragma unroll
    for (int off = 1; off < 16; off <<= 1)
#pragma unroll
        for (int i = 0; i < 4; i++)
#pragma unroll
            for (int r = 0; r < 4; r++)
                rsum[i][r] += __shfl_xor(rsum[i][r], off, 64);
    if (l16 == 0) {
#pragma unroll
        for (int i = 0; i < 4; i++)
#pragma unroll
            for (int r = 0; r < 4; r++) redB[i * 16 + quad * 4 + r][wave] = rsum[i][r];
    }
    __syncthreads();          // (also drains V half0 loads)

    float* ap = attn + (long)z * SLEN * SLEN;
#pragma unroll
    for (int i = 0; i < 4; i++)
#pragma unroll
        for (int r = 0; r < 4; r++) {
            f32x4 v = *reinterpret_cast<const f32x4*>(&redB[i * 16 + quad * 4 + r][0]);
            float inv = 1.0f / (v[0] + v[1] + v[2] + v[3]);
            long row = m0 + i * 16 + quad * 4 + r;
#pragma unroll
            for (int j = 0; j < 8; j++) {
                int col = (wave << 7) + j * 16 + l16;
                float p = acc[i][j][r] * inv;
                acc[i][j][r] = p;
                ap[row * SLEN + col] = p;
            }
        }

    if (wave < 2) {
#pragma unroll
        for (int i = 0; i < 4; i++)
#pragma unroll
            for (int j = 0; j < 8; j++) {
                int cl = (wave << 7) + j * 16 + l16;
#pragma unroll
                for (int r = 0; r < 4; r++) {
                    int row = i * 16 + quad * 4 + r;
                    int slot = (cl >> 3) ^ (row & 7);
                    *(u16*)((char*)Ph + row * 512 + slot * 16 + (cl & 7) * 2) = f2bs(acc[i][j][r]);
                }
            }
    }
    __syncthreads();          // Ph half0 + Vh half0 ready

    f32x4 acc2[4];
#pragma unroll
    for (int j = 0; j < 4; j++) acc2[j] = (f32x4){0.f, 0.f, 0.f, 0.f};

#pragma unroll
    for (int step = 0; step < 8; step++) {
        int Prow = (wave << 4) + l16;
        int aslot = (step * 4 + quad) ^ (Prow & 7);
        bf16x8 af = *reinterpret_cast<const bf16x8*>((char*)Ph + Prow * 512 + aslot * 16);
#pragma unroll
        for (int j = 0; j < 4; j++) {
            int hd = j * 16 + l16;
            int bslot = (step * 4 + quad) ^ (hd & 7);
            bf16x8 bf = *reinterpret_cast<const bf16x8*>((char*)Vh + hd * 512 + bslot * 16);
            acc2[j] = __builtin_amdgcn_mfma_f32_16x16x32_bf16(af, bf, acc2[j], 0, 0, 0);
        }
    }
    __syncthreads();          // all reads of half0 regions done

    {
        const u16* Vb = Vtbase + 256;
#pragma unroll
        for (int i = 0; i < 8; i++) {
            int o = wave * 8192 + i * 1024 + lane * 16;
            int hd = o >> 9, c = (o >> 4) & 31, g = c ^ (hd & 7);
            gload_lds16(Vb + (long)hd * SLEN + g * 8, (char*)Vh + wave * 8192 + i * 1024);
        }
    }
    if (wave >= 2) {
#pragma unroll
        for (int i = 0; i < 4; i++)
#pragma unroll
            for (int j = 0; j < 8; j++) {
                int cl = ((wave - 2) << 7) + j * 16 + l16;
#pragma unroll
                for (int r = 0; r < 4; r++) {
                    int row = i * 16 + quad * 4 + r;
                    int slot = (cl >> 3) ^ (row & 7);
                    *(u16*)((char*)Ph + row * 512 + slot * 16 + (cl & 7) * 2) = f2bs(acc[i][j][r]);
                }
            }
    }
    __syncthreads();          // Ph half1 + Vh half1 ready

#pragma unroll
    for (int step = 0; step < 8; step++) {
        int Prow = (wave << 4) + l16;
        int aslot = (step * 4 + quad) ^ (Prow & 7);
        bf16x8 af = *reinterpret_cast<const bf16x8*>((char*)Ph + Prow * 512 + aslot * 16);
#pragma unroll
        for (int j = 0; j < 4; j++) {
            int hd = j * 16 + l16;
            int bslot = (step * 4 + quad) ^ (hd & 7);
            bf16x8 bf = *reinterpret_cast<const bf16x8*>((char*)Vh + hd * 512 + bslot * 16);
            acc2[j] = __builtin_amdgcn_mfma_f32_16x16x32_bf16(af, bf, acc2[j], 0, 0, 0);
        }
    }

#pragma unroll
    for (int j = 0; j < 4; j++)
#pragma unroll
        for (int r = 0; r < 4; r++) {
            int q = m0 + (wave << 4) + quad * 4 + r;
            ob[((long)(b * SLEN + q)) * DMODEL + h * HDIM + j * 16 + l16] = f2bs(acc2[j][r]);
        }
}

// --- bf16 MFMA GEMM: 8-wave blocks, BK=64, depth-2 counted-vmcnt, swizzled --
// + T1 XCD-chunked bijective blockIdx swizzle (all 2D grids here %8==0)
template<int BM, int BN, int OUTBF, int GELU, int QKVF>
__global__ __launch_bounds__(512) void gemm_bf16(
    const u16* __restrict__ A, int lda, long sA1, long sA2,
    const u16* __restrict__ B, int ldb, long sB1, long sB2,
    void* __restrict__ Cv, int ldc, long sC1, long sC2,
    int zdiv, const float* __restrict__ bias,
    int N, int K, float scale, u16* __restrict__ vt)
{
    __shared__ u16 As[2][BM][64];
    __shared__ u16 Bs[2][BN][64];
    int z = blockIdx.z;
    int zq = z / zdiv, zr = z - zq * zdiv;
    A += zq * sA1 + zr * sA2;
    B += zq * sB1 + zr * sB2;

    // XCD-aware chunked swizzle of the 2D grid (bijective when nb%8==0)
    int nx = gridDim.x, ny = gridDim.y;
    int lin = blockIdx.x + nx * blockIdx.y;
    int nb = nx * ny;
    if ((nb & 7) == 0) lin = (lin & 7) * (nb >> 3) + (lin >> 3);
    int bx = lin % nx, by = lin / nx;

    int m0 = by * BM;
    int n0 = bx * BN;
    int tid = threadIdx.x;
    int wave = tid >> 6, lane = tid & 63;
    int quad = lane >> 4, l16 = lane & 15;
    int wr = wave >> 2, wc = wave & 3;           // 2 x 4 wave grid
    constexpr int MR = BM / 32, NR = BN / 64;    // fragments per wave
    constexpr int PA = BM / 64, PB = BN / 64;    // staging passes
    constexpr int LPT = PA + PB;                 // gloads per WAVE per tile

    f32x4 acc[MR][NR];
#pragma unroll
    for (int i = 0; i < MR; i++)
#pragma unroll
        for (int j = 0; j < NR; j++) acc[i][j] = (f32x4){0.f, 0.f, 0.f, 0.f};

    auto stage = [&](int buf, int k0) {
#pragma unroll
        for (int p = 0; p < PA; p++) {
            int chunk = p * 512 + tid;               // 16B chunk id, 8 per row
            int row = chunk >> 3, sc = chunk & 7;
            int gcol = (sc ^ (row & 7)) * 8;         // pre-swizzled source chunk
            gload_lds16(A + (long)(m0 + row) * lda + k0 + gcol,
                        (char*)&As[buf][0][0] + p * 8192 + wave * 1024);
        }
#pragma unroll
        for (int p = 0; p < PB; p++) {
            int chunk = p * 512 + tid;
            int row = chunk >> 3, sc = chunk & 7;
            int grow = n0 + row;
            if (grow > N - 1) grow = N - 1;          // tail: dup reads, masked later
            int gcol = (sc ^ (row & 7)) * 8;
            gload_lds16(B + (long)grow * ldb + k0 + gcol,
                        (char*)&Bs[buf][0][0] + p * 8192 + wave * 1024);
        }
    };

    int nt = K >> 6;                                 // BK = 64
    stage(0, 0);
    if (nt > 1) stage(1, 64);

    for (int t = 0; t < nt; ++t) {
        if (t + 1 < nt) waitv<LPT>();                // next tile may stay in flight
        else            waitv<0>();
        __builtin_amdgcn_s_barrier();
        __builtin_amdgcn_sched_barrier(0);

        int cur = t & 1;
#pragma unroll
        for (int kh = 0; kh < 2; kh++) {             // two 32-K halves
            bf16x8 afr[MR], bfr[NR];
#pragma unroll
            for (int i = 0; i < MR; i++) {
                int row = wr * (BM / 2) + i * 16 + l16;
                int slot = ((kh << 2) + quad) ^ (row & 7);
                afr[i] = *reinterpret_cast<const bf16x8*>(
                    (char*)&As[cur][0][0] + row * 128 + slot * 16);
            }
#pragma unroll
            for (int j = 0; j < NR; j++) {
                int row = wc * (BN / 4) + j * 16 + l16;
                int slot = ((kh << 2) + quad) ^ (row & 7);
                bfr[j] = *reinterpret_cast<const bf16x8*>(
                    (char*)&Bs[cur][0][0] + row * 128 + slot * 16);
            }
            __builtin_amdgcn_s_setprio(1);
#pragma unroll
            for (int i = 0; i < MR; i++)
#pragma unroll
                for (int j = 0; j < NR; j++)
                    acc[i][j] = __builtin_amdgcn_mfma_f32_16x16x32_bf16(afr[i], bfr[j], acc[i][j], 0, 0, 0);
            __builtin_amdgcn_s_setprio(0);
        }

        asm volatile("" ::: "memory");
        __builtin_amdgcn_sched_barrier(0);
        __builtin_amdgcn_s_barrier();                // all reads of buf done
        __builtin_amdgcn_sched_barrier(0);
        if (t + 2 < nt) stage(cur, (t + 2) << 6);
    }

    float* Cf = (float*)Cv;
    u16*   Cb = (u16*)Cv;
    long coff = zq * sC1 + zr * sC2;
#pragma unroll
    for (int i = 0; i < MR; i++) {
        int rbase = m0 + wr * (BM / 2) + i * 16 + quad * 4;
#pragma unroll
        for (int j = 0; j < NR; j++) {
            int col = n0 + wc * (BN / 4) + j * 16 + l16;
            if (col < N) {
                float badd = bias ? bias[col] : 0.f;
                u16x4 v4;
#pragma unroll
                for (int r = 0; r < 4; r++) {
                    float vv = acc[i][j][r] * scale + badd;
                    if (GELU) vv = 0.5f * vv * (1.0f + erff(vv * 0.70710678118f));
                    long idx = coff + (long)(rbase + r) * ldc + col;
                    if (OUTBF) { u16 u = f2bs(vv); Cb[idx] = u; v4[r] = u; }
                    else       Cf[idx] = vv;
                }
                if (QKVF && col >= 2 * DMODEL) {
                    int hh = (col - 2 * DMODEL) >> 6, hd = col & 63;
                    int bb = rbase >> 9, s = rbase & (SLEN - 1);
                    *reinterpret_cast<u16x4*>(
                        vt + ((long)(bb * NHEAD + hh) * HDIM + hd) * SLEN + s) = v4;
                }
            }
        }
    }
}

template<int BM, int BN, int OUTBF, int GELU, int QKVF = 0>
static inline void launch_gemm(hipStream_t stream,
    const u16* A, int lda, long sA1, long sA2,
    const u16* B, int ldb, long sB1, long sB2,
    void* C, int ldc, long sC1, long sC2,
    int zdiv, const float* bias, int M, int N, int K, float scale, int Z,
    u16* vt = nullptr)
{
    dim3 grid((N + BN - 1) / BN, M / BM, Z);
    gemm_bf16<BM, BN, OUTBF, GELU, QKVF><<<grid, 512, 0, stream>>>(
        A, lda, sA1, sA2, B, ldb, sB1, sB2, C, ldc, sC1, sC2,
        zdiv, bias, N, K, scale, vt);
}

// ---------------- driver ----------------
extern "C" void kernel_launch(void* const* d_in, const int* in_sizes, int n_in,
                              void* d_out, int out_size, void* d_ws, size_t ws_size,
                              hipStream_t stream)
{
    const int*   ids   = (const int*)d_in[0];
    const int*   amask = (const int*)d_in[1];
    const float* word  = (const float*)d_in[2];
    const float* pos   = (const float*)d_in[3];
    const float* seg   = (const float*)d_in[4];
    const float* eg    = (const float*)d_in[5];
    const float* eb    = (const float*)d_in[6];
    const float* Wq    = (const float*)d_in[7];
    const float* Wk    = (const float*)d_in[8];
    const float* Wv    = (const float*)d_in[9];
    const float* Wo    = (const float*)d_in[10];
    const float* F1w   = (const float*)d_in[11];
    const float* F1b   = (const float*)d_in[12];
    const float* F2w   = (const float*)d_in[13];
    const float* F2b   = (const float*)d_in[14];
    const float* G1    = (const float*)d_in[15];
    const float* B1    = (const float*)d_in[16];
    const float* G2    = (const float*)d_in[17];
    const float* B2    = (const float*)d_in[18];
    const float* OutW  = (const float*)d_in[19];
    const float* OutB  = (const float*)d_in[20];

    float* logits = (float*)d_out;
    float* attn_base = logits + (long)NTOK * VOCAB;

    long nd = (long)NTOK * DMODEL;
    // f32 region
    float* x  = (float*)d_ws;          // NTOK x D
    float* x1 = x + nd;                // NTOK x D
    float* p0 = x1 + nd;               // NTOK x D partials
    float* p1 = p0 + nd;
    // bf16 region
    u16* xb   = (u16*)(p1 + nd);                       // NTOK x D
    u16* x1b  = xb + nd;                               // NTOK x D
    u16* qkvb = x1b + nd;                              // NTOK x 3D
    u16* vtb  = qkvb + (long)NTOK * 3 * DMODEL;        // B*H x HD x S == nd
    u16* ob   = vtb + nd;                              // NTOK x D
    u16* hb   = ob + nd;                               // NTOK x F
    u16* wT   = hb + (long)NTOK * FDIM;                // 12 x LAYER_W_ELEMS
    u16* owT  = wT + (long)NLAYER * LAYER_W_ELEMS;     // [VOCAB][D]

    conv_all_kernel<<<TILES_ALL + TILES_OW, 256, 0, stream>>>(
        Wq, Wk, Wv, Wo, F1w, F2w, OutW, wT, owT);

    embed_ln_kernel<<<NTOK, 256, 0, stream>>>(ids, word, pos, seg, eg, eb, x, xb);

    for (int l = 0; l < NLAYER; l++) {
        const u16* qkvT = wT + (long)l * LAYER_W_ELEMS;
        const u16* woT  = qkvT + 3 * DD;
        const u16* f1T  = qkvT + 4 * DD;
        const u16* f2T  = qkvT + 4 * DD + DF;
        const float* f1b = F1b + (long)l * FDIM;
        const float* f2b = F2b + (long)l * DMODEL;
        float* attn_l = attn_base + (long)l * NBATCH * NHEAD * SLEN * SLEN;

        // fused QKV: [NTOK,768] @ [768,2304] -> qkvb bf16 (+ V scattered into vtb)
        launch_gemm<128, 64, 1, 0, 1>(stream, xb, DMODEL, 0, 0,
                                      qkvT, DMODEL, 0, 0,
                                      qkvb, 3 * DMODEL, 0, 0,
                                      1, nullptr, NTOK, 3 * DMODEL, DMODEL, 1.f, 1, vtb);

        // fused QK^T + mask + softmax + PV -> attn_l (f32) + ob (bf16)
        attn_kernel<<<dim3(SLEN / 64, NBATCH * NHEAD), 256, 0, stream>>>(
            qkvb, vtb, amask, attn_l, ob);

        // o @ Wo, split-K=2 -> p0,p1  (k-chunk 384)
        launch_gemm<128, 64, 0, 0>(stream, ob, DMODEL, 384, 0,
                                   woT, DMODEL, 384, 0,
                                   p0, DMODEL, nd, 0,
                                   1, nullptr, NTOK, DMODEL, 384, 1.f, 2);

        ln_res2_kernel<<<NTOK, 256, 0, stream>>>(x, p0, p1, nullptr,
                                                 G1 + (long)l * DMODEL, B1 + (long)l * DMODEL, x1, x1b);

        // h = gelu(x1 @ f1w + f1b)  -> hb bf16
        launch_gemm<128, 64, 1, 1>(stream, x1b, DMODEL, 0, 0,
                                   f1T, DMODEL, 0, 0,
                                   hb, FDIM, 0, 0,
                                   1, f1b, NTOK, FDIM, DMODEL, 1.f, 1);

        // FF2 split-K=2: partial s covers k in [s*1536, s*1536+1536)
        launch_gemm<128, 64, 0, 0>(stream, hb, FDIM, 1536, 0,
                                   f2T, FDIM, 1536, 0,
                                   p0, DMODEL, nd, 0,
                                   1, nullptr, NTOK, DMODEL, 1536, 1.f, 2);

        ln_res2_kernel<<<NTOK, 256, 0, stream>>>(x1, p0, p1, f2b,
                                                 G2 + (long)l * DMODEL, B2 + (long)l * DMODEL, x, xb);
    }

    // logits = x @ out_w + out_b
    launch_gemm<128, 128, 0, 0>(stream, xb, DMODEL, 0, 0,
                                owT, DMODEL, 0, 0,
                                logits, VOCAB, 0, 0,
                                1, OutB, NTOK, VOCAB, DMODEL, 1.f, 1);
}

// Round 10
// 1692.540 us; speedup vs baseline: 1.0369x; 1.0369x over previous
//
#include <hip/hip_runtime.h>
#include <hip/hip_bf16.h>

#define NLAYER 12
#define DMODEL 768
#define NHEAD  12
#define HDIM   64
#define FDIM   3072
#define VOCAB  30522
#define SLEN   512
#define NBATCH 4
#define NTOK   (NBATCH*SLEN)
#define EPSLN  1e-5f

typedef unsigned short u16;
using bf16 = __hip_bfloat16;
typedef __bf16 bf16x8 __attribute__((ext_vector_type(8)));
typedef float  f32x4  __attribute__((ext_vector_type(4)));
typedef u16    u16x4  __attribute__((ext_vector_type(4)));

__device__ __forceinline__ u16 f2bs(float f) {
    bf16 h = __float2bfloat16(f);
    return *reinterpret_cast<u16*>(&h);
}

// async global->LDS, 16B per lane. LDS dest = wave-uniform base + lane*16.
__device__ __forceinline__ void gload_lds16(const void* g, void* l) {
    auto gp = (const __attribute__((address_space(1))) unsigned int*)g;
    auto lp = (__attribute__((address_space(3))) unsigned int*)(unsigned long long)l;
    __builtin_amdgcn_global_load_lds(gp, lp, 16, 0, 0);
}

template<int N> __device__ __forceinline__ void waitv() {
    if constexpr (N == 0)      asm volatile("s_waitcnt vmcnt(0)" ::: "memory");
    else if constexpr (N == 3) asm volatile("s_waitcnt vmcnt(3)" ::: "memory");
    else if constexpr (N == 4) asm volatile("s_waitcnt vmcnt(4)" ::: "memory");
    else if constexpr (N == 6) asm volatile("s_waitcnt vmcnt(6)" ::: "memory");
    else if constexpr (N == 8) asm volatile("s_waitcnt vmcnt(8)" ::: "memory");
}

// ---------------- reductions ----------------
__device__ __forceinline__ float wave_sum64(float v) {
#pragma unroll
    for (int off = 32; off > 0; off >>= 1) v += __shfl_down(v, off, 64);
    return v;
}
__device__ __forceinline__ float block_sum256(float v, float* red) {
    v = wave_sum64(v);
    __syncthreads();
    if ((threadIdx.x & 63) == 0) red[threadIdx.x >> 6] = v;
    __syncthreads();
    return red[0] + red[1] + red[2] + red[3];
}

// ---------------- embedding + LN (writes f32 + bf16) ----------------
__global__ __launch_bounds__(256) void embed_ln_kernel(
    const int* __restrict__ ids, const float* __restrict__ word,
    const float* __restrict__ pos, const float* __restrict__ seg,
    const float* __restrict__ g, const float* __restrict__ b,
    float* __restrict__ out, u16* __restrict__ outb)
{
    __shared__ float red[4];
    int t = blockIdx.x;
    int s = t & (SLEN - 1);
    long woff = (long)ids[t] * DMODEL;
    float vals[3];
#pragma unroll
    for (int i = 0; i < 3; i++) {
        int d = threadIdx.x + i * 256;
        vals[i] = word[woff + d] + pos[(long)s * DMODEL + d] + seg[d];
    }
    float mu = block_sum256(vals[0] + vals[1] + vals[2], red) * (1.0f / DMODEL);
    float vv = 0.f;
#pragma unroll
    for (int i = 0; i < 3; i++) { float d0 = vals[i] - mu; vv += d0 * d0; }
    float rstd = rsqrtf(block_sum256(vv, red) * (1.0f / DMODEL) + EPSLN);
#pragma unroll
    for (int i = 0; i < 3; i++) {
        int d = threadIdx.x + i * 256;
        float r = (vals[i] - mu) * rstd * g[d] + b[d];
        out[(long)t * DMODEL + d] = r;
        outb[(long)t * DMODEL + d] = f2bs(r);
    }
}

// ------------- residual + 2 partials (+opt bias) + LN ----------------------
__global__ __launch_bounds__(256) void ln_res2_kernel(
    const float* __restrict__ a, const float* __restrict__ p0,
    const float* __restrict__ p1, const float* __restrict__ cbias,
    const float* __restrict__ g, const float* __restrict__ beta,
    float* __restrict__ out, u16* __restrict__ outb)
{
    __shared__ float red[4];
    long t = blockIdx.x;
    float vals[3];
#pragma unroll
    for (int i = 0; i < 3; i++) {
        int d = threadIdx.x + i * 256;
        float bb = cbias ? cbias[d] : 0.f;
        vals[i] = a[t * DMODEL + d] + p0[t * DMODEL + d] + p1[t * DMODEL + d] + bb;
    }
    float mu = block_sum256(vals[0] + vals[1] + vals[2], red) * (1.0f / DMODEL);
    float vv = 0.f;
#pragma unroll
    for (int i = 0; i < 3; i++) { float d0 = vals[i] - mu; vv += d0 * d0; }
    float rstd = rsqrtf(block_sum256(vv, red) * (1.0f / DMODEL) + EPSLN);
#pragma unroll
    for (int i = 0; i < 3; i++) {
        int d = threadIdx.x + i * 256;
        float r = (vals[i] - mu) * rstd * g[d] + beta[d];
        out[t * DMODEL + d] = r;
        outb[t * DMODEL + d] = f2bs(r);
    }
}

// ---------------- all-weights transpose-convert, ONE launch ----------------
#define DD (DMODEL*DMODEL)
#define DF (DMODEL*FDIM)
#define LAYER_W_ELEMS (4*DD + 2*DF)
#define TILES_DD 576
#define TILES_DF 2304
#define TILES_LAYER (4*TILES_DD + 2*TILES_DF)
#define TILES_ALL (NLAYER*TILES_LAYER)
#define NTX_OW ((VOCAB + 31) / 32)
#define TILES_OW (NTX_OW * (DMODEL/32))

__global__ __launch_bounds__(256) void conv_all_kernel(
    const float* __restrict__ Wq, const float* __restrict__ Wk,
    const float* __restrict__ Wv, const float* __restrict__ Wo,
    const float* __restrict__ F1w, const float* __restrict__ F2w,
    const float* __restrict__ OutW, u16* __restrict__ wT, u16* __restrict__ owT)
{
    __shared__ float t[32][33];
    int id = blockIdx.x;
    const float* src; u16* dst; int K, N, tt;
    if (id < TILES_ALL) {
        int l = id / TILES_LAYER, r = id - l * TILES_LAYER;
        u16* base = wT + (long)l * LAYER_W_ELEMS;
        if (r < TILES_DD)           { src = Wq  + (long)l * DD; dst = base;            K = DMODEL; N = DMODEL; tt = r; }
        else if (r < 2 * TILES_DD)  { src = Wk  + (long)l * DD; dst = base + DD;       K = DMODEL; N = DMODEL; tt = r - TILES_DD; }
        else if (r < 3 * TILES_DD)  { src = Wv  + (long)l * DD; dst = base + 2 * DD;   K = DMODEL; N = DMODEL; tt = r - 2 * TILES_DD; }
        else if (r < 4 * TILES_DD)  { src = Wo  + (long)l * DD; dst = base + 3 * DD;   K = DMODEL; N = DMODEL; tt = r - 3 * TILES_DD; }
        else if (r < 4 * TILES_DD + TILES_DF)
                                    { src = F1w + (long)l * DF; dst = base + 4 * DD;   K = DMODEL; N = FDIM;   tt = r - 4 * TILES_DD; }
        else                        { src = F2w + (long)l * DF; dst = base + 4 * DD + DF; K = FDIM; N = DMODEL; tt = r - 4 * TILES_DD - TILES_DF; }
    } else {
        src = OutW; dst = owT; K = DMODEL; N = VOCAB; tt = id - TILES_ALL;
    }
    int ntx = (N + 31) >> 5;
    int n0 = (tt % ntx) * 32, k0 = (tt / ntx) * 32;
    int tx = threadIdx.x & 31, ty = threadIdx.x >> 5;
#pragma unroll
    for (int i = 0; i < 32; i += 8) {
        int k = k0 + ty + i, n = n0 + tx;
        t[ty + i][tx] = (k < K && n < N) ? src[(long)k * N + n] : 0.f;
    }
    __syncthreads();
#pragma unroll
    for (int i = 0; i < 32; i += 8) {
        int n = n0 + ty + i, k = k0 + tx;
        if (n < N && k < K) dst[(long)n * K + k] = f2bs(t[tx][ty + i]);
    }
}

// -------- fused QK^T + mask + softmax + PV  (one kernel per 64 Q-rows) -----
__global__ __launch_bounds__(256, 2) void attn_kernel(
    const u16* __restrict__ qkvb, const u16* __restrict__ vtb,
    const int* __restrict__ amask,
    float* __restrict__ attn, u16* __restrict__ ob)
{
    __shared__ u16 Qs[64][64];
    __shared__ u16 Ks[SLEN][64];
    __shared__ float maskadd[SLEN];
    __shared__ __align__(16) float redA[64][4];
    __shared__ __align__(16) float redB[64][4];

    u16* Ph = &Ks[0][0];
    u16* Vh = &Ks[256][0];

    int z = blockIdx.y;
    int b = z / NHEAD, h = z - b * NHEAD;
    int m0 = blockIdx.x * 64;
    int tid = threadIdx.x;
    int wave = tid >> 6, lane = tid & 63;
    int quad = lane >> 4, l16 = lane & 15;
    const float scale2 = 0.036084391824351615f * 1.4426950408889634f; // (1/sqrt768)*log2e

    for (int i = tid; i < SLEN; i += 256)
        maskadd[i] = amask[b * SLEN + i] ? 0.f : -1e30f;

    const u16* Qbase = qkvb + (long)(b * SLEN) * (3 * DMODEL) + h * HDIM;
    const u16* Kbase = Qbase + DMODEL;
    const u16* Vtbase = vtb + (long)z * HDIM * SLEN;

#pragma unroll
    for (int i = 0; i < 2; i++) {
        int off = wave * 2048 + i * 1024 + lane * 16;
        int row = off >> 7, c = (off >> 4) & 7, g = c ^ (row & 7);
        gload_lds16(Qbase + (long)(m0 + row) * (3 * DMODEL) + g * 8,
                    (char*)&Qs[0][0] + wave * 2048 + i * 1024);
    }
#pragma unroll
    for (int i = 0; i < 16; i++) {
        int off = wave * 16384 + i * 1024 + lane * 16;
        int row = off >> 7, c = (off >> 4) & 7, g = c ^ (row & 7);
        gload_lds16(Kbase + (long)row * (3 * DMODEL) + g * 8,
                    (char*)&Ks[0][0] + wave * 16384 + i * 1024);
    }
    __syncthreads();

    f32x4 acc[4][8];
#pragma unroll
    for (int i = 0; i < 4; i++)
#pragma unroll
        for (int j = 0; j < 8; j++) acc[i][j] = (f32x4){0.f, 0.f, 0.f, 0.f};

#pragma unroll
    for (int ks = 0; ks < 2; ks++) {
        bf16x8 afr[4], bfr[8];
#pragma unroll
        for (int i = 0; i < 4; i++) {
            int row = i * 16 + l16;
            int slot = ((ks << 2) + quad) ^ (row & 7);
            afr[i] = *reinterpret_cast<const bf16x8*>((char*)&Qs[0][0] + row * 128 + slot * 16);
        }
#pragma unroll
        for (int j = 0; j < 8; j++) {
            int row = wave * 128 + j * 16 + l16;
            int slot = ((ks << 2) + quad) ^ (row & 7);
            bfr[j] = *reinterpret_cast<const bf16x8*>((char*)&Ks[0][0] + row * 128 + slot * 16);
        }
#pragma unroll
        for (int i = 0; i < 4; i++)
#pragma unroll
            for (int j = 0; j < 8; j++)
                acc[i][j] = __builtin_amdgcn_mfma_f32_16x16x32_bf16(afr[i], bfr[j], acc[i][j], 0, 0, 0);
    }

    // fold scale*log2e + mask into acc once (scaled-exp2 domain)
    {
        float ma[8];
#pragma unroll
        for (int j = 0; j < 8; j++) ma[j] = maskadd[wave * 128 + j * 16 + l16];
#pragma unroll
        for (int i = 0; i < 4; i++)
#pragma unroll
            for (int j = 0; j < 8; j++)
#pragma unroll
                for (int r = 0; r < 4; r++)
                    acc[i][j][r] = acc[i][j][r] * scale2 + ma[j];
    }

    float rmax[4][4];
#pragma unroll
    for (int i = 0; i < 4; i++)
#pragma unroll
        for (int r = 0; r < 4; r++) {
            float m = -3e38f;
#pragma unroll
            for (int j = 0; j < 8; j++) m = fmaxf(m, acc[i][j][r]);
            rmax[i][r] = m;
        }
#pragma unroll
    for (int off = 1; off < 16; off <<= 1)
#pragma unroll
        for (int i = 0; i < 4; i++)
#pragma unroll
            for (int r = 0; r < 4; r++)
                rmax[i][r] = fmaxf(rmax[i][r], __shfl_xor(rmax[i][r], off, 64));
    if (l16 == 0) {
#pragma unroll
        for (int i = 0; i < 4; i++)
#pragma unroll
            for (int r = 0; r < 4; r++) redA[i * 16 + quad * 4 + r][wave] = rmax[i][r];
    }
    __syncthreads();          // all waves done reading Ks; safe to restage V

    {
        const u16* Vb = Vtbase + 0;
#pragma unroll
        for (int i = 0; i < 8; i++) {
            int o = wave * 8192 + i * 1024 + lane * 16;
            int hd = o >> 9, c = (o >> 4) & 31, g = c ^ (hd & 7);
            gload_lds16(Vb + (long)hd * SLEN + g * 8, (char*)Vh + wave * 8192 + i * 1024);
        }
    }

#pragma unroll
    for (int i = 0; i < 4; i++)
#pragma unroll
        for (int r = 0; r < 4; r++) {
            f32x4 v = *reinterpret_cast<const f32x4*>(&redA[i * 16 + quad * 4 + r][0]);
            rmax[i][r] = fmaxf(fmaxf(v[0], v[1]), fmaxf(v[2], v[3]));
        }

    float rsum[4][4];
#pragma unroll
    for (int i = 0; i < 4; i++)
#pragma unroll
        for (int r = 0; r < 4; r++) {
            float s = 0.f;
#pragma unroll
            for (int j = 0; j < 8; j++) {
                float e = __builtin_amdgcn_exp2f(acc[i][j][r] - rmax[i][r]);
                acc[i][j][r] = e;
                s += e;
            }
            rsum[i][r] = s;
        }
#pragma unroll
    for (int off = 1; off < 16; off <<= 1)
#pragma unroll
        for (int i = 0; i < 4; i++)
#pragma unroll
            for (int r = 0; r < 4; r++)
                rsum[i][r] += __shfl_xor(rsum[i][r], off, 64);
    if (l16 == 0) {
#pragma unroll
        for (int i = 0; i < 4; i++)
#pragma unroll
            for (int r = 0; r < 4; r++) redB[i * 16 + quad * 4 + r][wave] = rsum[i][r];
    }
    __syncthreads();          // (also drains V half0 loads)

    float* ap = attn + (long)z * SLEN * SLEN;
#pragma unroll
    for (int i = 0; i < 4; i++)
#pragma unroll
        for (int r = 0; r < 4; r++) {
            f32x4 v = *reinterpret_cast<const f32x4*>(&redB[i * 16 + quad * 4 + r][0]);
            float inv = 1.0f / (v[0] + v[1] + v[2] + v[3]);
            long row = m0 + i * 16 + quad * 4 + r;
#pragma unroll
            for (int j = 0; j < 8; j++) {
                int col = (wave << 7) + j * 16 + l16;
                float p = acc[i][j][r] * inv;
                acc[i][j][r] = p;
                ap[row * SLEN + col] = p;
            }
        }

    if (wave < 2) {
#pragma unroll
        for (int i = 0; i < 4; i++)
#pragma unroll
            for (int j = 0; j < 8; j++) {
                int cl = (wave << 7) + j * 16 + l16;
#pragma unroll
                for (int r = 0; r < 4; r++) {
                    int row = i * 16 + quad * 4 + r;
                    int slot = (cl >> 3) ^ (row & 7);
                    *(u16*)((char*)Ph + row * 512 + slot * 16 + (cl & 7) * 2) = f2bs(acc[i][j][r]);
                }
            }
    }
    __syncthreads();          // Ph half0 + Vh half0 ready

    f32x4 acc2[4];
#pragma unroll
    for (int j = 0; j < 4; j++) acc2[j] = (f32x4){0.f, 0.f, 0.f, 0.f};

#pragma unroll
    for (int step = 0; step < 8; step++) {
        int Prow = (wave << 4) + l16;
        int aslot = (step * 4 + quad) ^ (Prow & 7);
        bf16x8 af = *reinterpret_cast<const bf16x8*>((char*)Ph + Prow * 512 + aslot * 16);
#pragma unroll
        for (int j = 0; j < 4; j++) {
            int hd = j * 16 + l16;
            int bslot = (step * 4 + quad) ^ (hd & 7);
            bf16x8 bf = *reinterpret_cast<const bf16x8*>((char*)Vh + hd * 512 + bslot * 16);
            acc2[j] = __builtin_amdgcn_mfma_f32_16x16x32_bf16(af, bf, acc2[j], 0, 0, 0);
        }
    }
    __syncthreads();          // all reads of half0 regions done

    {
        const u16* Vb = Vtbase + 256;
#pragma unroll
        for (int i = 0; i < 8; i++) {
            int o = wave * 8192 + i * 1024 + lane * 16;
            int hd = o >> 9, c = (o >> 4) & 31, g = c ^ (hd & 7);
            gload_lds16(Vb + (long)hd * SLEN + g * 8, (char*)Vh + wave * 8192 + i * 1024);
        }
    }
    if (wave >= 2) {
#pragma unroll
        for (int i = 0; i < 4; i++)
#pragma unroll
            for (int j = 0; j < 8; j++) {
                int cl = ((wave - 2) << 7) + j * 16 + l16;
#pragma unroll
                for (int r = 0; r < 4; r++) {
                    int row = i * 16 + quad * 4 + r;
                    int slot = (cl >> 3) ^ (row & 7);
                    *(u16*)((char*)Ph + row * 512 + slot * 16 + (cl & 7) * 2) = f2bs(acc[i][j][r]);
                }
            }
    }
    __syncthreads();          // Ph half1 + Vh half1 ready

#pragma unroll
    for (int step = 0; step < 8; step++) {
        int Prow = (wave << 4) + l16;
        int aslot = (step * 4 + quad) ^ (Prow & 7);
        bf16x8 af = *reinterpret_cast<const bf16x8*>((char*)Ph + Prow * 512 + aslot * 16);
#pragma unroll
        for (int j = 0; j < 4; j++) {
            int hd = j * 16 + l16;
            int bslot = (step * 4 + quad) ^ (hd & 7);
            bf16x8 bf = *reinterpret_cast<const bf16x8*>((char*)Vh + hd * 512 + bslot * 16);
            acc2[j] = __builtin_amdgcn_mfma_f32_16x16x32_bf16(af, bf, acc2[j], 0, 0, 0);
        }
    }

#pragma unroll
    for (int j = 0; j < 4; j++)
#pragma unroll
        for (int r = 0; r < 4; r++) {
            int q = m0 + (wave << 4) + quad * 4 + r;
            ob[((long)(b * SLEN + q)) * DMODEL + h * HDIM + j * 16 + l16] = f2bs(acc2[j][r]);
        }
}

// --- bf16 MFMA GEMM: 8-wave blocks, BK=64, depth-2 counted-vmcnt, swizzled --
// C[z] = epi( scale * A[z] @ B[z]^T + bias ),  A:[M][K] bf16, B:[N][K] bf16
template<int BM, int BN, int OUTBF, int GELU, int QKVF>
__global__ __launch_bounds__(512) void gemm_bf16(
    const u16* __restrict__ A, int lda, long sA1, long sA2,
    const u16* __restrict__ B, int ldb, long sB1, long sB2,
    void* __restrict__ Cv, int ldc, long sC1, long sC2,
    int zdiv, const float* __restrict__ bias,
    int N, int K, float scale, u16* __restrict__ vt)
{
    __shared__ u16 As[2][BM][64];
    __shared__ u16 Bs[2][BN][64];
    int z = blockIdx.z;
    int zq = z / zdiv, zr = z - zq * zdiv;
    A += zq * sA1 + zr * sA2;
    B += zq * sB1 + zr * sB2;

    int m0 = blockIdx.y * BM;
    int n0 = blockIdx.x * BN;
    int tid = threadIdx.x;
    int wave = tid >> 6, lane = tid & 63;
    int quad = lane >> 4, l16 = lane & 15;
    int wr = wave >> 2, wc = wave & 3;           // 2 x 4 wave grid
    constexpr int MR = BM / 32, NR = BN / 64;    // fragments per wave
    constexpr int PA = BM / 64, PB = BN / 64;    // staging passes
    constexpr int LPT = PA + PB;                 // gloads per WAVE per tile

    f32x4 acc[MR][NR];
#pragma unroll
    for (int i = 0; i < MR; i++)
#pragma unroll
        for (int j = 0; j < NR; j++) acc[i][j] = (f32x4){0.f, 0.f, 0.f, 0.f};

    auto stage = [&](int buf, int k0) {
#pragma unroll
        for (int p = 0; p < PA; p++) {
            int chunk = p * 512 + tid;               // 16B chunk id, 8 per row
            int row = chunk >> 3, sc = chunk & 7;
            int gcol = (sc ^ (row & 7)) * 8;         // pre-swizzled source chunk
            gload_lds16(A + (long)(m0 + row) * lda + k0 + gcol,
                        (char*)&As[buf][0][0] + p * 8192 + wave * 1024);
        }
#pragma unroll
        for (int p = 0; p < PB; p++) {
            int chunk = p * 512 + tid;
            int row = chunk >> 3, sc = chunk & 7;
            int grow = n0 + row;
            if (grow > N - 1) grow = N - 1;          // tail: dup reads, masked later
            int gcol = (sc ^ (row & 7)) * 8;
            gload_lds16(B + (long)grow * ldb + k0 + gcol,
                        (char*)&Bs[buf][0][0] + p * 8192 + wave * 1024);
        }
    };

    int nt = K >> 6;                                 // BK = 64
    stage(0, 0);
    if (nt > 1) stage(1, 64);

    for (int t = 0; t < nt; ++t) {
        if (t + 1 < nt) waitv<LPT>();                // next tile may stay in flight
        else            waitv<0>();
        __builtin_amdgcn_s_barrier();
        __builtin_amdgcn_sched_barrier(0);

        int cur = t & 1;
#pragma unroll
        for (int kh = 0; kh < 2; kh++) {             // two 32-K halves
            bf16x8 afr[MR], bfr[NR];
#pragma unroll
            for (int i = 0; i < MR; i++) {
                int row = wr * (BM / 2) + i * 16 + l16;
                int slot = ((kh << 2) + quad) ^ (row & 7);
                afr[i] = *reinterpret_cast<const bf16x8*>(
                    (char*)&As[cur][0][0] + row * 128 + slot * 16);
            }
#pragma unroll
            for (int j = 0; j < NR; j++) {
                int row = wc * (BN / 4) + j * 16 + l16;
                int slot = ((kh << 2) + quad) ^ (row & 7);
                bfr[j] = *reinterpret_cast<const bf16x8*>(
                    (char*)&Bs[cur][0][0] + row * 128 + slot * 16);
            }
            __builtin_amdgcn_s_setprio(1);
#pragma unroll
            for (int i = 0; i < MR; i++)
#pragma unroll
                for (int j = 0; j < NR; j++)
                    acc[i][j] = __builtin_amdgcn_mfma_f32_16x16x32_bf16(afr[i], bfr[j], acc[i][j], 0, 0, 0);
            __builtin_amdgcn_s_setprio(0);
        }

        asm volatile("" ::: "memory");
        __builtin_amdgcn_sched_barrier(0);
        __builtin_amdgcn_s_barrier();                // all reads of buf done
        __builtin_amdgcn_sched_barrier(0);
        if (t + 2 < nt) stage(cur, (t + 2) << 6);
    }

    float* Cf = (float*)Cv;
    u16*   Cb = (u16*)Cv;
    long coff = zq * sC1 + zr * sC2;
#pragma unroll
    for (int i = 0; i < MR; i++) {
        int rbase = m0 + wr * (BM / 2) + i * 16 + quad * 4;
#pragma unroll
        for (int j = 0; j < NR; j++) {
            int col = n0 + wc * (BN / 4) + j * 16 + l16;
            if (col < N) {
                float badd = bias ? bias[col] : 0.f;
                u16x4 v4;
#pragma unroll
                for (int r = 0; r < 4; r++) {
                    float vv = acc[i][j][r] * scale + badd;
                    if (GELU) vv = 0.5f * vv * (1.0f + erff(vv * 0.70710678118f));
                    long idx = coff + (long)(rbase + r) * ldc + col;
                    if (OUTBF) { u16 u = f2bs(vv); Cb[idx] = u; v4[r] = u; }
                    else       Cf[idx] = vv;
                }
                if (QKVF && col >= 2 * DMODEL) {
                    int hh = (col - 2 * DMODEL) >> 6, hd = col & 63;
                    int bb = rbase >> 9, s = rbase & (SLEN - 1);
                    *reinterpret_cast<u16x4*>(
                        vt + ((long)(bb * NHEAD + hh) * HDIM + hd) * SLEN + s) = v4;
                }
            }
        }
    }
}

template<int BM, int BN, int OUTBF, int GELU, int QKVF = 0>
static inline void launch_gemm(hipStream_t stream,
    const u16* A, int lda, long sA1, long sA2,
    const u16* B, int ldb, long sB1, long sB2,
    void* C, int ldc, long sC1, long sC2,
    int zdiv, const float* bias, int M, int N, int K, float scale, int Z,
    u16* vt = nullptr)
{
    dim3 grid((N + BN - 1) / BN, M / BM, Z);
    gemm_bf16<BM, BN, OUTBF, GELU, QKVF><<<grid, 512, 0, stream>>>(
        A, lda, sA1, sA2, B, ldb, sB1, sB2, C, ldc, sC1, sC2,
        zdiv, bias, N, K, scale, vt);
}

// --- persistent-tile GEMM (f32 out + bias): blocks loop over tiles with the
// depth-2 counted-vmcnt pipeline CONTINUOUS across tile boundaries.
// Used for logits (3824 tiles >> 512-block capacity).
template<int BM, int BN>
__global__ __launch_bounds__(512) void gemm_pers(
    const u16* __restrict__ A, int lda,
    const u16* __restrict__ B, int ldb,
    float* __restrict__ C, int ldc,
    const float* __restrict__ bias,
    int N, int K, int ntiles, int nx)
{
    __shared__ u16 As[2][BM][64];
    __shared__ u16 Bs[2][BN][64];
    int tid = threadIdx.x;
    int wave = tid >> 6, lane = tid & 63;
    int quad = lane >> 4, l16 = lane & 15;
    int wr = wave >> 2, wc = wave & 3;
    constexpr int MR = BM / 32, NR = BN / 64;
    constexpr int PA = BM / 64, PB = BN / 64;
    constexpr int LPT = PA + PB;

    int G = gridDim.x;
    int nt = K >> 6;
    if ((int)blockIdx.x >= ntiles) return;
    int myTiles = (ntiles - 1 - (int)blockIdx.x) / G + 1;
    int steps = myTiles * nt;

    f32x4 acc[MR][NR];
#pragma unroll
    for (int i = 0; i < MR; i++)
#pragma unroll
        for (int j = 0; j < NR; j++) acc[i][j] = (f32x4){0.f, 0.f, 0.f, 0.f};

    // staging cursor (tile id, k-chunk)
    int sg = blockIdx.x, sk = 0;
    auto stageC = [&](int buf) {
        int by = sg / nx, bx = sg - by * nx;
        int m0 = by * BM, n0 = bx * BN;
        int k0 = sk << 6;
#pragma unroll
        for (int p = 0; p < PA; p++) {
            int chunk = p * 512 + tid;
            int row = chunk >> 3, sc = chunk & 7;
            int gcol = (sc ^ (row & 7)) * 8;
            gload_lds16(A + (long)(m0 + row) * lda + k0 + gcol,
                        (char*)&As[buf][0][0] + p * 8192 + wave * 1024);
        }
#pragma unroll
        for (int p = 0; p < PB; p++) {
            int chunk = p * 512 + tid;
            int row = chunk >> 3, sc = chunk & 7;
            int grow = n0 + row;
            if (grow > N - 1) grow = N - 1;
            int gcol = (sc ^ (row & 7)) * 8;
            gload_lds16(B + (long)grow * ldb + k0 + gcol,
                        (char*)&Bs[buf][0][0] + p * 8192 + wave * 1024);
        }
        if (++sk == nt) { sk = 0; sg += G; }
    };

    stageC(0);
    if (steps > 1) stageC(1);

    int cg = blockIdx.x, ck = 0;       // compute cursor
    for (int s = 0; s < steps; ++s) {
        if (s + 1 < steps) waitv<LPT>();
        else               waitv<0>();
        __builtin_amdgcn_s_barrier();
        __builtin_amdgcn_sched_barrier(0);

        int cur = s & 1;
#pragma unroll
        for (int kh = 0; kh < 2; kh++) {
            bf16x8 afr[MR], bfr[NR];
#pragma unroll
            for (int i = 0; i < MR; i++) {
                int row = wr * (BM / 2) + i * 16 + l16;
                int slot = ((kh << 2) + quad) ^ (row & 7);
                afr[i] = *reinterpret_cast<const bf16x8*>(
                    (char*)&As[cur][0][0] + row * 128 + slot * 16);
            }
#pragma unroll
            for (int j = 0; j < NR; j++) {
                int row = wc * (BN / 4) + j * 16 + l16;
                int slot = ((kh << 2) + quad) ^ (row & 7);
                bfr[j] = *reinterpret_cast<const bf16x8*>(
                    (char*)&Bs[cur][0][0] + row * 128 + slot * 16);
            }
            __builtin_amdgcn_s_setprio(1);
#pragma unroll
            for (int i = 0; i < MR; i++)
#pragma unroll
                for (int j = 0; j < NR; j++)
                    acc[i][j] = __builtin_amdgcn_mfma_f32_16x16x32_bf16(afr[i], bfr[j], acc[i][j], 0, 0, 0);
            __builtin_amdgcn_s_setprio(0);
        }

        asm volatile("" ::: "memory");
        __builtin_amdgcn_sched_barrier(0);
        __builtin_amdgcn_s_barrier();               // buf free for restage
        __builtin_amdgcn_sched_barrier(0);
        if (s + 2 < steps) stageC(cur);

        if (ck == nt - 1) {
            // epilogue for finished tile cg (registers -> global; no LDS touch)
            int by = cg / nx, bx = cg - by * nx;
            int m0 = by * BM, n0 = bx * BN;
#pragma unroll
            for (int i = 0; i < MR; i++) {
                int rbase = m0 + wr * (BM / 2) + i * 16 + quad * 4;
#pragma unroll
                for (int j = 0; j < NR; j++) {
                    int col = n0 + wc * (BN / 4) + j * 16 + l16;
                    if (col < N) {
                        float badd = bias[col];
#pragma unroll
                        for (int r = 0; r < 4; r++)
                            C[(long)(rbase + r) * ldc + col] = acc[i][j][r] + badd;
                    }
#pragma unroll
                    for (int r = 0; r < 4; r++) acc[i][j][r] = 0.f;
                }
            }
            ck = 0; cg += G;
        } else {
            ++ck;
        }
    }
}

// ---------------- driver ----------------
extern "C" void kernel_launch(void* const* d_in, const int* in_sizes, int n_in,
                              void* d_out, int out_size, void* d_ws, size_t ws_size,
                              hipStream_t stream)
{
    const int*   ids   = (const int*)d_in[0];
    const int*   amask = (const int*)d_in[1];
    const float* word  = (const float*)d_in[2];
    const float* pos   = (const float*)d_in[3];
    const float* seg   = (const float*)d_in[4];
    const float* eg    = (const float*)d_in[5];
    const float* eb    = (const float*)d_in[6];
    const float* Wq    = (const float*)d_in[7];
    const float* Wk    = (const float*)d_in[8];
    const float* Wv    = (const float*)d_in[9];
    const float* Wo    = (const float*)d_in[10];
    const float* F1w   = (const float*)d_in[11];
    const float* F1b   = (const float*)d_in[12];
    const float* F2w   = (const float*)d_in[13];
    const float* F2b   = (const float*)d_in[14];
    const float* G1    = (const float*)d_in[15];
    const float* B1    = (const float*)d_in[16];
    const float* G2    = (const float*)d_in[17];
    const float* B2    = (const float*)d_in[18];
    const float* OutW  = (const float*)d_in[19];
    const float* OutB  = (const float*)d_in[20];

    float* logits = (float*)d_out;
    float* attn_base = logits + (long)NTOK * VOCAB;

    long nd = (long)NTOK * DMODEL;
    // f32 region
    float* x  = (float*)d_ws;          // NTOK x D
    float* x1 = x + nd;                // NTOK x D
    float* p0 = x1 + nd;               // NTOK x D partials
    float* p1 = p0 + nd;
    // bf16 region
    u16* xb   = (u16*)(p1 + nd);                       // NTOK x D
    u16* x1b  = xb + nd;                               // NTOK x D
    u16* qkvb = x1b + nd;                              // NTOK x 3D
    u16* vtb  = qkvb + (long)NTOK * 3 * DMODEL;        // B*H x HD x S == nd
    u16* ob   = vtb + nd;                              // NTOK x D
    u16* hb   = ob + nd;                               // NTOK x F
    u16* wT   = hb + (long)NTOK * FDIM;                // 12 x LAYER_W_ELEMS
    u16* owT  = wT + (long)NLAYER * LAYER_W_ELEMS;     // [VOCAB][D]

    conv_all_kernel<<<TILES_ALL + TILES_OW, 256, 0, stream>>>(
        Wq, Wk, Wv, Wo, F1w, F2w, OutW, wT, owT);

    embed_ln_kernel<<<NTOK, 256, 0, stream>>>(ids, word, pos, seg, eg, eb, x, xb);

    for (int l = 0; l < NLAYER; l++) {
        const u16* qkvT = wT + (long)l * LAYER_W_ELEMS;
        const u16* woT  = qkvT + 3 * DD;
        const u16* f1T  = qkvT + 4 * DD;
        const u16* f2T  = qkvT + 4 * DD + DF;
        const float* f1b = F1b + (long)l * FDIM;
        const float* f2b = F2b + (long)l * DMODEL;
        float* attn_l = attn_base + (long)l * NBATCH * NHEAD * SLEN * SLEN;

        // fused QKV: [NTOK,768] @ [768,2304] -> qkvb bf16 (+ V scattered into vtb)
        launch_gemm<128, 64, 1, 0, 1>(stream, xb, DMODEL, 0, 0,
                                      qkvT, DMODEL, 0, 0,
                                      qkvb, 3 * DMODEL, 0, 0,
                                      1, nullptr, NTOK, 3 * DMODEL, DMODEL, 1.f, 1, vtb);

        // fused QK^T + mask + softmax + PV -> attn_l (f32) + ob (bf16)
        attn_kernel<<<dim3(SLEN / 64, NBATCH * NHEAD), 256, 0, stream>>>(
            qkvb, vtb, amask, attn_l, ob);

        // o @ Wo, split-K=2 -> p0,p1  (k-chunk 384)
        launch_gemm<128, 64, 0, 0>(stream, ob, DMODEL, 384, 0,
                                   woT, DMODEL, 384, 0,
                                   p0, DMODEL, nd, 0,
                                   1, nullptr, NTOK, DMODEL, 384, 1.f, 2);

        ln_res2_kernel<<<NTOK, 256, 0, stream>>>(x, p0, p1, nullptr,
                                                 G1 + (long)l * DMODEL, B1 + (long)l * DMODEL, x1, x1b);

        // h = gelu(x1 @ f1w + f1b)  -> hb bf16
        launch_gemm<128, 64, 1, 1>(stream, x1b, DMODEL, 0, 0,
                                   f1T, DMODEL, 0, 0,
                                   hb, FDIM, 0, 0,
                                   1, f1b, NTOK, FDIM, DMODEL, 1.f, 1);

        // FF2 split-K=2: partial s covers k in [s*1536, s*1536+1536)
        launch_gemm<128, 64, 0, 0>(stream, hb, FDIM, 1536, 0,
                                   f2T, FDIM, 1536, 0,
                                   p0, DMODEL, nd, 0,
                                   1, nullptr, NTOK, DMODEL, 1536, 1.f, 2);

        ln_res2_kernel<<<NTOK, 256, 0, stream>>>(x1, p0, p1, f2b,
                                                 G2 + (long)l * DMODEL, B2 + (long)l * DMODEL, x, xb);
    }

    // logits = x @ out_w + out_b  — persistent-tile GEMM (3824 tiles on 512 blocks)
    {
        int nx = (VOCAB + 127) / 128;          // 239
        int ntiles = nx * (NTOK / 128);        // 3824
        gemm_pers<128, 128><<<512, 512, 0, stream>>>(
            xb, DMODEL, owT, DMODEL, logits, VOCAB, OutB, VOCAB, DMODEL, ntiles, nx);
    }
}